// Round 3
// baseline (1102.980 us; speedup 1.0000x reference)
//
#include <hip/hip_runtime.h>
#include <hip/hip_bf16.h>

#define DIM 1024
#define NGROUPS 32
#define GSIZE 32
#define TT 1024
#define BB 16
#define MROWS (TT*BB)          // 16384 rows for all batched GEMMs
#define BD (BB*DIM)            // 16384 elems per timestep slab
#define PF 16                  // scan prefetch depth (must divide TT, power of 2)

typedef __attribute__((ext_vector_type(8))) short short8;
typedef __attribute__((ext_vector_type(4))) float f32x4;

// ---------- helpers ----------
__device__ __forceinline__ ushort f2b(float v) {
  __hip_bfloat16 b = __float2bfloat16(v);
  return *reinterpret_cast<ushort*>(&b);
}
__device__ __forceinline__ float b2f(ushort u) {
  __hip_bfloat16 b; *reinterpret_cast<ushort*>(&b) = u;
  return __bfloat162float(b);
}
__device__ __forceinline__ float softplusf(float z) {
  return (z > 20.f) ? z : log1pf(expf(z));
}
__device__ __forceinline__ float sigmoidf_(float z) { return 1.f/(1.f+expf(-z)); }

#define AS1(p) ((__attribute__((address_space(1))) void*)(void*)(p))
#define AS3(p) ((__attribute__((address_space(3))) void*)(void*)(p))

// ---------- split x into bf16 hi/lo ----------
__global__ __launch_bounds__(256) void split_x_kernel(
    const float4* __restrict__ x, ushort4* __restrict__ xh, ushort4* __restrict__ xl, int n4) {
  int i = blockIdx.x*256 + threadIdx.x;
  int stride = gridDim.x*256;
  for (; i < n4; i += stride) {
    float4 v = x[i];
    ushort4 h, l;
    h.x = f2b(v.x); l.x = f2b(v.x - b2f(h.x));
    h.y = f2b(v.y); l.y = f2b(v.y - b2f(h.y));
    h.z = f2b(v.z); l.z = f2b(v.z - b2f(h.z));
    h.w = f2b(v.w); l.w = f2b(v.w - b2f(h.w));
    xh[i] = h; xl[i] = l;
  }
}

// ---------- split/convert weights ----------
__global__ __launch_bounds__(256) void split_w_kernel(
    const float4* __restrict__ wx, const float4* __restrict__ wa,
    const float4* __restrict__ wd, const float4* __restrict__ wo,
    ushort4* __restrict__ wxh, ushort4* __restrict__ wxl,
    ushort4* __restrict__ wah, ushort4* __restrict__ wdh,
    ushort4* __restrict__ woh, int n4) {
  int i = blockIdx.x*256 + threadIdx.x;
  if (i >= n4) return;
  float4 v = wx[i];
  ushort4 h, l;
  h.x = f2b(v.x); l.x = f2b(v.x - b2f(h.x));
  h.y = f2b(v.y); l.y = f2b(v.y - b2f(h.y));
  h.z = f2b(v.z); l.z = f2b(v.z - b2f(h.z));
  h.w = f2b(v.w); l.w = f2b(v.w - b2f(h.w));
  wxh[i] = h; wxl[i] = l;
  float4 a = wa[i];
  ushort4 ha; ha.x=f2b(a.x); ha.y=f2b(a.y); ha.z=f2b(a.z); ha.w=f2b(a.w);
  wah[i] = ha;
  float4 d = wd[i];
  ushort4 hd; hd.x=f2b(d.x); hd.y=f2b(d.y); hd.z=f2b(d.z); hd.w=f2b(d.w);
  wdh[i] = hd;
  float4 o = wo[i];
  ushort4 ho; ho.x=f2b(o.x); ho.y=f2b(o.y); ho.z=f2b(o.z); ho.w=f2b(o.w);
  woh[i] = ho;
}

// ---------- GEMM: C[m][n] = sum_k A[m][k]*B[n][k]  (both row-major, N=K=1024) ----------
// NT=3: A,B given as hi+lo bf16 splits; acc = Ah*Bh + Ah*Bl + Al*Bh (~fp32 accurate)
// EPI: 0: +bias  1: 1+softplus(+bias)  2: sigmoid(+bias)  3: extra * silu(acc)
// Grid is flattened knowledge: gridDim == (8, 128). XCD-aware swizzle (T1):
// dispatch-linear did -> XCD k = did&7 owns 16 contiguous row-panels; all 8
// col-blocks of a row-panel land on the same XCD (A-panel L2 reuse).
template<int NT, int EPI>
__global__ __launch_bounds__(256) void gemm_kernel(
    const ushort* __restrict__ Ah, const ushort* __restrict__ Al,
    const ushort* __restrict__ Bh, const ushort* __restrict__ Bl,
    const float* __restrict__ bias, const float* __restrict__ extra,
    float* __restrict__ C)
{
  __shared__ ushort As [128*32];
  __shared__ ushort Bs [128*32];
  __shared__ ushort AsL[(NT==3)?128*32:8];
  __shared__ ushort BsL[(NT==3)?128*32:8];

  const int tid  = threadIdx.x;
  const int lane = tid & 63;
  const int wid  = tid >> 6;
  const int wr   = wid >> 1, wc = wid & 1;

  // XCD swizzle: did in [0,1024), bijective.
  const int did   = blockIdx.y * 8 + blockIdx.x;
  const int xcd   = did & 7;
  const int j     = did >> 3;
  const int m0    = (xcd * 16 + (j >> 3)) * 128;   // row-panel
  const int n0    = (j & 7) * 128;                  // col-panel

  f32x4 acc[4][4];
  #pragma unroll
  for (int i=0;i<4;++i)
    #pragma unroll
    for (int jj=0;jj<4;++jj) acc[i][jj] = f32x4{0.f,0.f,0.f,0.f};

  const int fr = lane & 15;
  const int kq = (lane >> 4) * 8;

  for (int ks = 0; ks < DIM/32; ++ks) {
    const int k0 = ks*32;
    #pragma unroll
    for (int jl = 0; jl < 2; ++jl) {
      int idx = jl*256 + tid;
      int row = idx >> 2;
      int kk  = (idx & 3)*8;
      size_t goffA = (size_t)(m0+row)*DIM + k0 + kk;
      size_t goffB = (size_t)(n0+row)*DIM + k0 + kk;
      __builtin_amdgcn_global_load_lds(AS1(Ah+goffA), AS3(As+idx*8), 16, 0, 0);
      __builtin_amdgcn_global_load_lds(AS1(Bh+goffB), AS3(Bs+idx*8), 16, 0, 0);
      if constexpr (NT==3) {
        __builtin_amdgcn_global_load_lds(AS1(Al+goffA), AS3(AsL+idx*8), 16, 0, 0);
        __builtin_amdgcn_global_load_lds(AS1(Bl+goffB), AS3(BsL+idx*8), 16, 0, 0);
      }
    }
    __syncthreads();

    short8 ah[4], bh[4], al[4], bl[4];
    #pragma unroll
    for (int f=0; f<4; ++f) {
      ah[f] = *(const short8*)&As[(wr*64+f*16+fr)*32 + kq];
      bh[f] = *(const short8*)&Bs[(wc*64+f*16+fr)*32 + kq];
      if constexpr (NT==3) {
        al[f] = *(const short8*)&AsL[(wr*64+f*16+fr)*32 + kq];
        bl[f] = *(const short8*)&BsL[(wc*64+f*16+fr)*32 + kq];
      }
    }
    #pragma unroll
    for (int fi=0; fi<4; ++fi)
      #pragma unroll
      for (int fj=0; fj<4; ++fj) {
        acc[fi][fj] = __builtin_amdgcn_mfma_f32_16x16x32_bf16(ah[fi], bh[fj], acc[fi][fj], 0,0,0);
        if constexpr (NT==3) {
          acc[fi][fj] = __builtin_amdgcn_mfma_f32_16x16x32_bf16(ah[fi], bl[fj], acc[fi][fj], 0,0,0);
          acc[fi][fj] = __builtin_amdgcn_mfma_f32_16x16x32_bf16(al[fi], bh[fj], acc[fi][fj], 0,0,0);
        }
      }
    __syncthreads();
  }

  #pragma unroll
  for (int fi=0; fi<4; ++fi)
    #pragma unroll
    for (int fj=0; fj<4; ++fj)
      #pragma unroll
      for (int r=0; r<4; ++r) {
        int row = m0 + wr*64 + fi*16 + (lane>>4)*4 + r;
        int col = n0 + wc*64 + fj*16 + (lane&15);
        float c = acc[fi][fj][r];
        float val;
        if constexpr (EPI==0)      val = c + bias[col];
        else if constexpr (EPI==1) val = 1.f + softplusf(c + bias[col]);
        else if constexpr (EPI==2) val = sigmoidf_(c + bias[col]);
        else                       val = extra[(size_t)row*DIM + col] * (c * sigmoidf_(c));
        C[(size_t)row*DIM + col] = val;
      }
}

// ---------- elementwise recurrence scan (16384 independent chains) ----------
// Latency-bound fix: register ring-buffer prefetch, depth PF=16, fully
// unrolled so all ring indices are compile-time constants (no scratch).
// Loads for step t+PF are issued while computing step t — 48 loads in
// flight covers ~900cy HBM latency at ~45cy/step chain.
__global__ __launch_bounds__(64) void scan_kernel(
    const float* __restrict__ vx, const float* __restrict__ al,
    const float* __restrict__ dl, const float* __restrict__ rh,
    const float* __restrict__ h0, float* __restrict__ hout,
    ushort* __restrict__ Hb)
{
  int tid = blockIdx.x*64 + threadIdx.x;   // 0..16383 == b*DIM+e
  int e = tid & (DIM-1);
  float r = rh[e];
  float h = h0[tid];
  hout[tid] = h;                            // h[0] = h0

  float pv[PF], pa[PF], pd[PF];
  #pragma unroll
  for (int p = 0; p < PF; ++p) {
    size_t base = (size_t)p*BD + tid;
    pv[p] = vx[base]; pa[p] = al[base]; pd[p] = dl[base];
  }

  #pragma unroll PF
  for (int t = 0; t < TT; ++t) {
    const int slot = t & (PF-1);            // static after unroll
    float v = fmaf(r, h, pv[slot]);
    float a = pa[slot];
    float d = pd[slot];
    if (t < TT-PF) {                        // prefetch step t+PF into slot
      size_t nb = (size_t)(t+PF)*BD + tid;
      pv[slot] = vx[nb]; pa[slot] = al[nb]; pd[slot] = dl[nb];
    }
    float av = fminf(fmaxf(fabsf(v), 1e-6f), 10.0f);
    float cand = copysignf(exp2f(a * log2f(av)), v);
    h = fmaf(d, cand - h, h);               // (1-d)h + d*cand
    hout[(size_t)(t+1)*BD + tid] = h;
    Hb[(size_t)t*BD + tid] = f2b(h);
  }
}

// ---------- compete softmax over contiguous groups of 32 ----------
__global__ __launch_bounds__(256) void compete_kernel(
    const float* __restrict__ h, float* __restrict__ comp)
{
  int g = blockIdx.x*256 + threadIdx.x;     // 524288 groups
  const float4* p = (const float4*)(h + (size_t)g*GSIZE);
  float vals[32];
  #pragma unroll
  for (int j = 0; j < 8; ++j) {
    float4 t4 = p[j];
    vals[4*j+0]=t4.x; vals[4*j+1]=t4.y; vals[4*j+2]=t4.z; vals[4*j+3]=t4.w;
  }
  float m = vals[0];
  #pragma unroll
  for (int j = 1; j < 32; ++j) m = fmaxf(m, vals[j]);
  float s = 0.f;
  #pragma unroll
  for (int j = 0; j < 32; ++j) { vals[j] = expf(vals[j]-m); s += vals[j]; }
  float inv = 1.f/s;
  float4* o = (float4*)(comp + (size_t)g*GSIZE);
  #pragma unroll
  for (int j = 0; j < 8; ++j) {
    float4 t4; t4.x=vals[4*j]*inv; t4.y=vals[4*j+1]*inv; t4.z=vals[4*j+2]*inv; t4.w=vals[4*j+3]*inv;
    o[j] = t4;
  }
}

extern "C" void kernel_launch(void* const* d_in, const int* in_sizes, int n_in,
                              void* d_out, int out_size, void* d_ws, size_t ws_size,
                              hipStream_t stream) {
  const float* x       = (const float*)d_in[0];
  const float* h0      = (const float*)d_in[1];
  const float* W_x     = (const float*)d_in[2];
  const float* r_h     = (const float*)d_in[3];
  const float* b       = (const float*)d_in[4];
  const float* W_alpha = (const float*)d_in[5];
  const float* b_alpha = (const float*)d_in[6];
  const float* W_delta = (const float*)d_in[7];
  const float* b_delta = (const float*)d_in[8];
  const float* W_out   = (const float*)d_in[9];

  float* out   = (float*)d_out;
  float* h_out = out;                                   // (T+1)*B*D
  float* outs  = out + (size_t)(TT+1)*BD;               // T*B*D
  float* vx    = outs;                                  // scratch until final GEMM

  char* p = (char*)d_ws;
  ushort* Xh  = (ushort*)p; p += (size_t)MROWS*DIM*2;
  ushort* Xl  = (ushort*)p; p += (size_t)MROWS*DIM*2;
  ushort* Wxh = (ushort*)p; p += (size_t)DIM*DIM*2;
  ushort* Wxl = (ushort*)p; p += (size_t)DIM*DIM*2;
  ushort* Wah = (ushort*)p; p += (size_t)DIM*DIM*2;
  ushort* Wdh = (ushort*)p; p += (size_t)DIM*DIM*2;
  ushort* Woh = (ushort*)p; p += (size_t)DIM*DIM*2;
  float*  alphaf = (float*)p; p += (size_t)MROWS*DIM*4;
  float*  deltaf = (float*)p; p += (size_t)MROWS*DIM*4;
  ushort* Hb  = (ushort*)p; p += (size_t)MROWS*DIM*2;
  float*  comp = (float*)p; p += (size_t)MROWS*DIM*4;

  split_x_kernel<<<2048, 256, 0, stream>>>((const float4*)x, (ushort4*)Xh, (ushort4*)Xl, MROWS*DIM/4);
  split_w_kernel<<<1024, 256, 0, stream>>>((const float4*)W_x, (const float4*)W_alpha,
                                           (const float4*)W_delta, (const float4*)W_out,
                                           (ushort4*)Wxh, (ushort4*)Wxl, (ushort4*)Wah,
                                           (ushort4*)Wdh, (ushort4*)Woh, DIM*DIM/4);

  dim3 g(DIM/128, MROWS/128);
  gemm_kernel<3,0><<<g, 256, 0, stream>>>(Xh, Xl, Wxh, Wxl, b,       nullptr, vx);
  gemm_kernel<1,1><<<g, 256, 0, stream>>>(Xh, nullptr, Wah, nullptr, b_alpha, nullptr, alphaf);
  gemm_kernel<1,2><<<g, 256, 0, stream>>>(Xh, nullptr, Wdh, nullptr, b_delta, nullptr, deltaf);

  scan_kernel<<<256, 64, 0, stream>>>(vx, alphaf, deltaf, r_h, h0, h_out, Hb);

  compete_kernel<<<2048, 256, 0, stream>>>(h_out + (size_t)BD, comp);

  gemm_kernel<1,3><<<g, 256, 0, stream>>>(Hb, nullptr, Woh, nullptr, nullptr, comp, outs);
}

// Round 5
// 707.828 us; speedup vs baseline: 1.5583x; 1.5583x over previous
//
#include <hip/hip_runtime.h>
#include <hip/hip_bf16.h>
#include <hip/hip_fp16.h>

#define DIM 1024
#define NGROUPS 32
#define GSIZE 32
#define TT 1024
#define BB 16
#define MROWS (TT*BB)          // 16384 rows for all batched GEMMs
#define BD (BB*DIM)            // 16384 elems per timestep slab
#define G 16                   // scan group size (steps per reg buffer)
#define NG (TT/G)              // 64 groups (even)

typedef __attribute__((ext_vector_type(8))) short short8;
typedef __attribute__((ext_vector_type(4))) float f32x4;

// ---------- helpers ----------
__device__ __forceinline__ ushort f2b(float v) {
  __hip_bfloat16 b = __float2bfloat16(v);
  return *reinterpret_cast<ushort*>(&b);
}
__device__ __forceinline__ float b2f(ushort u) {
  __hip_bfloat16 b; *reinterpret_cast<ushort*>(&b) = u;
  return __bfloat162float(b);
}
__device__ __forceinline__ ushort f2h(float v) {
  __half h = __float2half(v);
  return *reinterpret_cast<ushort*>(&h);
}
__device__ __forceinline__ float softplusf(float z) {
  return (z > 20.f) ? z : log1pf(expf(z));
}
__device__ __forceinline__ float sigmoidf_(float z) { return 1.f/(1.f+expf(-z)); }

#define AS1(p) ((__attribute__((address_space(1))) void*)(void*)(p))
#define AS3(p) ((__attribute__((address_space(3))) void*)(void*)(p))

// ---------- split x into bf16 hi/lo ----------
__global__ __launch_bounds__(256) void split_x_kernel(
    const float4* __restrict__ x, ushort4* __restrict__ xh, ushort4* __restrict__ xl, int n4) {
  int i = blockIdx.x*256 + threadIdx.x;
  int stride = gridDim.x*256;
  for (; i < n4; i += stride) {
    float4 v = x[i];
    ushort4 h, l;
    h.x = f2b(v.x); l.x = f2b(v.x - b2f(h.x));
    h.y = f2b(v.y); l.y = f2b(v.y - b2f(h.y));
    h.z = f2b(v.z); l.z = f2b(v.z - b2f(h.z));
    h.w = f2b(v.w); l.w = f2b(v.w - b2f(h.w));
    xh[i] = h; xl[i] = l;
  }
}

// ---------- split/convert weights ----------
__global__ __launch_bounds__(256) void split_w_kernel(
    const float4* __restrict__ wx, const float4* __restrict__ wa,
    const float4* __restrict__ wd, const float4* __restrict__ wo,
    ushort4* __restrict__ wxh, ushort4* __restrict__ wxl,
    ushort4* __restrict__ wah, ushort4* __restrict__ wdh,
    ushort4* __restrict__ woh, int n4) {
  int i = blockIdx.x*256 + threadIdx.x;
  if (i >= n4) return;
  float4 v = wx[i];
  ushort4 h, l;
  h.x = f2b(v.x); l.x = f2b(v.x - b2f(h.x));
  h.y = f2b(v.y); l.y = f2b(v.y - b2f(h.y));
  h.z = f2b(v.z); l.z = f2b(v.z - b2f(h.z));
  h.w = f2b(v.w); l.w = f2b(v.w - b2f(h.w));
  wxh[i] = h; wxl[i] = l;
  float4 a = wa[i];
  ushort4 ha; ha.x=f2b(a.x); ha.y=f2b(a.y); ha.z=f2b(a.z); ha.w=f2b(a.w);
  wah[i] = ha;
  float4 d = wd[i];
  ushort4 hd; hd.x=f2b(d.x); hd.y=f2b(d.y); hd.z=f2b(d.z); hd.w=f2b(d.w);
  wdh[i] = hd;
  float4 o = wo[i];
  ushort4 ho; ho.x=f2b(o.x); ho.y=f2b(o.y); ho.z=f2b(o.z); ho.w=f2b(o.w);
  woh[i] = ho;
}

// ---------- GEMM: C[m][n] = sum_k A[m][k]*B[n][k]  (both row-major, N=K=1024) ----------
// NT=3: A,B given as hi+lo bf16 splits; acc = Ah*Bh + Ah*Bl + Al*Bh (~fp32 accurate)
// EPI 0/1/2 write into the packed scan record {f32 vx; f16 a; f16 d} (8B) at
//   rec = (row>>4)*BD + (row&15)*DIM + col   (row = t*16+b):
//   0: vx f32 @ +0    1: a=1+softplus f16 @ +4    2: d=sigmoid f16 @ +6
// EPI 3: C[row*DIM+col] = extra * silu(acc)   (float* C)
// XCD-aware swizzle (T1): gridDim == (8,128); linear did -> xcd = did&7 owns
// 16 contiguous row-panels; all 8 col-blocks of a row-panel on one XCD.
template<int NT, int EPI>
__global__ __launch_bounds__(256) void gemm_kernel(
    const ushort* __restrict__ Ah, const ushort* __restrict__ Al,
    const ushort* __restrict__ Bh, const ushort* __restrict__ Bl,
    const float* __restrict__ bias, const float* __restrict__ extra,
    void* __restrict__ Cv)
{
  __shared__ ushort As [128*32];
  __shared__ ushort Bs [128*32];
  __shared__ ushort AsL[(NT==3)?128*32:8];
  __shared__ ushort BsL[(NT==3)?128*32:8];

  const int tid  = threadIdx.x;
  const int lane = tid & 63;
  const int wid  = tid >> 6;
  const int wr   = wid >> 1, wc = wid & 1;

  const int did   = blockIdx.y * 8 + blockIdx.x;
  const int xcd   = did & 7;
  const int j     = did >> 3;
  const int m0    = (xcd * 16 + (j >> 3)) * 128;   // row-panel
  const int n0    = (j & 7) * 128;                  // col-panel

  f32x4 acc[4][4];
  #pragma unroll
  for (int i=0;i<4;++i)
    #pragma unroll
    for (int jj=0;jj<4;++jj) acc[i][jj] = f32x4{0.f,0.f,0.f,0.f};

  const int fr = lane & 15;
  const int kq = (lane >> 4) * 8;

  for (int ks = 0; ks < DIM/32; ++ks) {
    const int k0 = ks*32;
    #pragma unroll
    for (int jl = 0; jl < 2; ++jl) {
      int idx = jl*256 + tid;
      int row = idx >> 2;
      int kk  = (idx & 3)*8;
      size_t goffA = (size_t)(m0+row)*DIM + k0 + kk;
      size_t goffB = (size_t)(n0+row)*DIM + k0 + kk;
      __builtin_amdgcn_global_load_lds(AS1(Ah+goffA), AS3(As+idx*8), 16, 0, 0);
      __builtin_amdgcn_global_load_lds(AS1(Bh+goffB), AS3(Bs+idx*8), 16, 0, 0);
      if constexpr (NT==3) {
        __builtin_amdgcn_global_load_lds(AS1(Al+goffA), AS3(AsL+idx*8), 16, 0, 0);
        __builtin_amdgcn_global_load_lds(AS1(Bl+goffB), AS3(BsL+idx*8), 16, 0, 0);
      }
    }
    __syncthreads();

    short8 ah[4], bh[4], al[4], bl[4];
    #pragma unroll
    for (int f=0; f<4; ++f) {
      ah[f] = *(const short8*)&As[(wr*64+f*16+fr)*32 + kq];
      bh[f] = *(const short8*)&Bs[(wc*64+f*16+fr)*32 + kq];
      if constexpr (NT==3) {
        al[f] = *(const short8*)&AsL[(wr*64+f*16+fr)*32 + kq];
        bl[f] = *(const short8*)&BsL[(wc*64+f*16+fr)*32 + kq];
      }
    }
    #pragma unroll
    for (int fi=0; fi<4; ++fi)
      #pragma unroll
      for (int fj=0; fj<4; ++fj) {
        acc[fi][fj] = __builtin_amdgcn_mfma_f32_16x16x32_bf16(ah[fi], bh[fj], acc[fi][fj], 0,0,0);
        if constexpr (NT==3) {
          acc[fi][fj] = __builtin_amdgcn_mfma_f32_16x16x32_bf16(ah[fi], bl[fj], acc[fi][fj], 0,0,0);
          acc[fi][fj] = __builtin_amdgcn_mfma_f32_16x16x32_bf16(al[fi], bh[fj], acc[fi][fj], 0,0,0);
        }
      }
    __syncthreads();
  }

  #pragma unroll
  for (int fi=0; fi<4; ++fi)
    #pragma unroll
    for (int fj=0; fj<4; ++fj)
      #pragma unroll
      for (int r=0; r<4; ++r) {
        int row = m0 + wr*64 + fi*16 + (lane>>4)*4 + r;
        int col = n0 + wc*64 + fj*16 + (lane&15);
        float c = acc[fi][fj][r];
        if constexpr (EPI==3) {
          ((float*)Cv)[(size_t)row*DIM + col] =
              extra[(size_t)row*DIM + col] * (c * sigmoidf_(c));
        } else {
          size_t rec = (size_t)(row>>4)*BD + (size_t)(row&15)*DIM + col;
          char* base = (char*)Cv + rec*8;
          if constexpr (EPI==0)      *(float*)base = c + bias[col];
          else if constexpr (EPI==1) *(ushort*)(base+4) = f2h(1.f + softplusf(c + bias[col]));
          else                       *(ushort*)(base+6) = f2h(sigmoidf_(c + bias[col]));
        }
      }
}

// ---------- elementwise recurrence scan (16384 independent chains) ----------
// One 8B packed load per step {f32 vx; f16 a; f16 d}. Double-buffered groups
// of G=16 with sched_barrier(0) fences: loads of group g+1 are *emitted*
// before compute of group g (fixed order -> regs stay live -> true batching),
// overlapping ~900cy HBM latency with ~16*60cy of serial chain work.
#define SCAN_STEP(rc, t)                                                     \
  {                                                                          \
    uint bits = __float_as_uint((rc).y);                                     \
    __half ha_, hd_;                                                         \
    *reinterpret_cast<ushort*>(&ha_) = (ushort)(bits & 0xFFFF);              \
    *reinterpret_cast<ushort*>(&hd_) = (ushort)(bits >> 16);                 \
    float a = __half2float(ha_);                                             \
    float d = __half2float(hd_);                                             \
    float v = fmaf(r, h, (rc).x);                                            \
    float av = fminf(fmaxf(fabsf(v), 1e-6f), 10.0f);                         \
    float cand = copysignf(__builtin_amdgcn_exp2f(a * __builtin_amdgcn_logf(av)), v); \
    h = fmaf(d, cand - h, h);                                                \
    hout[(size_t)((t)+1)*BD + tid] = h;                                      \
    Hb[(size_t)(t)*BD + tid] = f2b(h);                                       \
  }

__global__ __launch_bounds__(64) void scan_kernel(
    const float2* __restrict__ pk, const float* __restrict__ rh,
    const float* __restrict__ h0, float* __restrict__ hout,
    ushort* __restrict__ Hb)
{
  int tid = blockIdx.x*64 + threadIdx.x;   // 0..16383 == b*DIM+e
  float r = rh[tid & (DIM-1)];
  float h = h0[tid];
  hout[tid] = h;                            // h[0] = h0

  float2 bufA[G], bufB[G];

  #pragma unroll
  for (int i = 0; i < G; ++i) bufA[i] = pk[(size_t)i*BD + tid];
  __builtin_amdgcn_sched_barrier(0);

  for (int gp = 0; gp < NG; gp += 2) {
    // issue loads for group gp+1 into B (in flight during compute of A)
    #pragma unroll
    for (int i = 0; i < G; ++i) bufB[i] = pk[(size_t)((gp+1)*G + i)*BD + tid];
    __builtin_amdgcn_sched_barrier(0);
    #pragma unroll
    for (int i = 0; i < G; ++i) { SCAN_STEP(bufA[i], gp*G + i); }
    __builtin_amdgcn_sched_barrier(0);
    // issue loads for group gp+2 into A (in flight during compute of B)
    if (gp + 2 < NG) {
      #pragma unroll
      for (int i = 0; i < G; ++i) bufA[i] = pk[(size_t)((gp+2)*G + i)*BD + tid];
    }
    __builtin_amdgcn_sched_barrier(0);
    #pragma unroll
    for (int i = 0; i < G; ++i) { SCAN_STEP(bufB[i], (gp+1)*G + i); }
    __builtin_amdgcn_sched_barrier(0);
  }
}

// ---------- compete softmax over contiguous groups of 32 ----------
__global__ __launch_bounds__(256) void compete_kernel(
    const float* __restrict__ h, float* __restrict__ comp)
{
  int g = blockIdx.x*256 + threadIdx.x;     // 524288 groups
  const float4* p = (const float4*)(h + (size_t)g*GSIZE);
  float vals[32];
  #pragma unroll
  for (int j = 0; j < 8; ++j) {
    float4 t4 = p[j];
    vals[4*j+0]=t4.x; vals[4*j+1]=t4.y; vals[4*j+2]=t4.z; vals[4*j+3]=t4.w;
  }
  float m = vals[0];
  #pragma unroll
  for (int j = 1; j < 32; ++j) m = fmaxf(m, vals[j]);
  float s = 0.f;
  #pragma unroll
  for (int j = 0; j < 32; ++j) { vals[j] = expf(vals[j]-m); s += vals[j]; }
  float inv = 1.f/s;
  float4* o = (float4*)(comp + (size_t)g*GSIZE);
  #pragma unroll
  for (int j = 0; j < 8; ++j) {
    float4 t4; t4.x=vals[4*j]*inv; t4.y=vals[4*j+1]*inv; t4.z=vals[4*j+2]*inv; t4.w=vals[4*j+3]*inv;
    o[j] = t4;
  }
}

extern "C" void kernel_launch(void* const* d_in, const int* in_sizes, int n_in,
                              void* d_out, int out_size, void* d_ws, size_t ws_size,
                              hipStream_t stream) {
  const float* x       = (const float*)d_in[0];
  const float* h0      = (const float*)d_in[1];
  const float* W_x     = (const float*)d_in[2];
  const float* r_h     = (const float*)d_in[3];
  const float* b       = (const float*)d_in[4];
  const float* W_alpha = (const float*)d_in[5];
  const float* b_alpha = (const float*)d_in[6];
  const float* W_delta = (const float*)d_in[7];
  const float* b_delta = (const float*)d_in[8];
  const float* W_out   = (const float*)d_in[9];

  float* out   = (float*)d_out;
  float* h_out = out;                                   // (T+1)*B*D
  float* outs  = out + (size_t)(TT+1)*BD;               // T*B*D

  char* p = (char*)d_ws;
  ushort* Xh  = (ushort*)p; p += (size_t)MROWS*DIM*2;   // 32MB
  ushort* Xl  = (ushort*)p; p += (size_t)MROWS*DIM*2;   // 32MB
  ushort* Wxh = (ushort*)p; p += (size_t)DIM*DIM*2;
  ushort* Wxl = (ushort*)p; p += (size_t)DIM*DIM*2;
  ushort* Wah = (ushort*)p; p += (size_t)DIM*DIM*2;
  ushort* Wdh = (ushort*)p; p += (size_t)DIM*DIM*2;
  ushort* Woh = (ushort*)p; p += (size_t)DIM*DIM*2;
  char*   pack = p;         p += (size_t)MROWS*DIM*8;   // 128MB {f32,f16,f16}
  ushort* Hb  = (ushort*)p; p += (size_t)MROWS*DIM*2;   // 32MB
  float*  comp = (float*)p; p += (size_t)MROWS*DIM*4;   // 64MB

  split_x_kernel<<<2048, 256, 0, stream>>>((const float4*)x, (ushort4*)Xh, (ushort4*)Xl, MROWS*DIM/4);
  split_w_kernel<<<1024, 256, 0, stream>>>((const float4*)W_x, (const float4*)W_alpha,
                                           (const float4*)W_delta, (const float4*)W_out,
                                           (ushort4*)Wxh, (ushort4*)Wxl, (ushort4*)Wah,
                                           (ushort4*)Wdh, (ushort4*)Woh, DIM*DIM/4);

  dim3 g(DIM/128, MROWS/128);
  gemm_kernel<3,0><<<g, 256, 0, stream>>>(Xh, Xl, Wxh, Wxl, b,       nullptr, pack);
  gemm_kernel<1,1><<<g, 256, 0, stream>>>(Xh, nullptr, Wah, nullptr, b_alpha, nullptr, pack);
  gemm_kernel<1,2><<<g, 256, 0, stream>>>(Xh, nullptr, Wdh, nullptr, b_delta, nullptr, pack);

  scan_kernel<<<256, 64, 0, stream>>>((const float2*)pack, r_h, h0, h_out, Hb);

  compete_kernel<<<2048, 256, 0, stream>>>(h_out + (size_t)BD, comp);

  gemm_kernel<1,3><<<g, 256, 0, stream>>>(Hb, nullptr, Woh, nullptr, nullptr, comp, outs);
}